// Round 4
// baseline (136.840 us; speedup 1.0000x reference)
//
#include <hip/hip_runtime.h>
#include <hip/hip_bf16.h>

#define NN 8192
#define FF 128
#define BM 64
#define BK 64
#define KS 8
#define KCH (NN / KS)      // 1024 K per block
#define NSTEP (KCH / BK)   // 16

typedef __attribute__((ext_vector_type(8))) short bf16x8;   // 8 bf16 (4 VGPR)
typedef __attribute__((ext_vector_type(4))) float f32x4;

__device__ __forceinline__ short f2bf(float f) {
  unsigned u = __float_as_uint(f);
  u += 0x7FFFu + ((u >> 16) & 1u);
  return (short)(u >> 16);
}
__device__ __forceinline__ float bf2f(short s) {
  return __uint_as_float(((unsigned)(unsigned short)s) << 16);
}

// ---- kernel 1: deg/dinv from f32 rowsums AND write bf16 copy of adj to ws ----
__global__ __launch_bounds__(256) void k_deg_cvt(const float* __restrict__ adj,
                                                 float* __restrict__ dinv,
                                                 short* __restrict__ abf) {
  const int row = blockIdx.x;
  const float4* p = (const float4*)(adj + (size_t)row * NN);
  short4* q = (short4*)(abf + (size_t)row * NN);
  float s = 0.f;
#pragma unroll
  for (int it = 0; it < 8; ++it) {
    float4 v = p[it * 256 + threadIdx.x];
    s += (v.x + v.y) + (v.z + v.w);
    short4 o;
    o.x = f2bf(v.x); o.y = f2bf(v.y); o.z = f2bf(v.z); o.w = f2bf(v.w);
    q[it * 256 + threadIdx.x] = o;
  }
#pragma unroll
  for (int off = 32; off > 0; off >>= 1) s += __shfl_down(s, off, 64);
  __shared__ float partial[4];
  if ((threadIdx.x & 63) == 0) partial[threadIdx.x >> 6] = s;
  __syncthreads();
  if (threadIdx.x == 0) {
    float deg = (partial[0] + partial[1]) + (partial[2] + partial[3]) + 1.0f;
    dinv[row] = 1.0f / sqrtf(deg + 1e-8f);
  }
}

// ---- kernel 2: yT[f][i] = dinv[i] * x[i][f]  (bf16, transposed for NT GEMM) ----
__global__ __launch_bounds__(256) void k_scale_t(const float* __restrict__ x,
                                                 const float* __restrict__ dinv,
                                                 short* __restrict__ yT) {
  __shared__ float tile[64][129];
  const int r0 = blockIdx.x * 64;
  const int tid = threadIdx.x;
#pragma unroll
  for (int it = 0; it < 8; ++it) {
    int q = it * 256 + tid;
    int r = q >> 5;
    int c = q & 31;
    float4 v = ((const float4*)(x + (size_t)(r0 + r) * FF))[c];
    float d = dinv[r0 + r];
    tile[r][c * 4 + 0] = v.x * d;
    tile[r][c * 4 + 1] = v.y * d;
    tile[r][c * 4 + 2] = v.z * d;
    tile[r][c * 4 + 3] = v.w * d;
  }
  __syncthreads();
  const int f = tid >> 1;
  const int i0 = (tid & 1) * 32;
#pragma unroll
  for (int g = 0; g < 4; ++g) {
    bf16x8 o;
#pragma unroll
    for (int j = 0; j < 8; ++j) o[j] = f2bf(tile[i0 + g * 8 + j][f]);
    *(bf16x8*)(yT + (size_t)f * NN + r0 + i0 + g * 8) = o;
  }
}

// ---- kernel 3: zpart[ks] = abf[:, ksliced] @ y  (bf16 MFMA, K-split) ----
// 1024 blocks (128 M-tiles x 8 K-slices), 512 thr = 8 waves (2M x 4N),
// BM=64, BN=128(all), BK=64. Single-LDS-buffer + 2-deep register prefetch;
// 2 blocks/CU overlap each other's barrier/latency stalls. A is bf16 from ws.
__global__ __launch_bounds__(512, 4) void k_gemm(const short* __restrict__ abf,
                                                 const short* __restrict__ yT,
                                                 short* __restrict__ zpart) {
  __shared__ short As[BM][72];     // +8 pad
  __shared__ short Bs[128][72];
  const int tid = threadIdx.x;
  const int wave = tid >> 6;
  const int lane = tid & 63;
  const int mb = 127 - (int)(blockIdx.x & 127);   // reverse: read L3-warm rows first
  const int ks = blockIdx.x >> 7;
  const int row0 = mb * BM;
  const size_t kbase = (size_t)ks * KCH;

  // staging maps: A = 64 rows x 64 bf16 (8/thread); B = 128 rows x 64 bf16
  const int s_ar = tid >> 3;
  const int s_ac = (tid & 7) * 8;
  const short* pa  = abf + (size_t)(row0 + s_ar) * NN + kbase + s_ac;
  const short* pb0 = yT + (size_t)s_ar * NN + kbase + s_ac;
  const short* pb1 = yT + (size_t)(s_ar + 64) * NN + kbase + s_ac;

  const int wm = (wave >> 2) * 32;   // 0/32
  const int wn = (wave & 3) * 32;    // 0/32/64/96
  const int fr = lane & 15;
  const int kh = (lane >> 4) * 8;

  f32x4 acc00 = {0.f,0.f,0.f,0.f}, acc01 = acc00, acc10 = acc00, acc11 = acc00;

  bf16x8 aX, aY, bX0, bX1, bY0, bY1;

#define LOADT(av, b0v, b1v, koff) do {                                         \
    av  = *(const bf16x8*)(pa  + (koff));                                      \
    b0v = *(const bf16x8*)(pb0 + (koff));                                      \
    b1v = *(const bf16x8*)(pb1 + (koff));                                      \
  } while (0)

#define STAGE(av, b0v, b1v) do {                                               \
    *(bf16x8*)&As[s_ar][s_ac] = av;                                            \
    *(bf16x8*)&Bs[s_ar][s_ac] = b0v;                                           \
    *(bf16x8*)&Bs[s_ar + 64][s_ac] = b1v;                                      \
  } while (0)

#define COMPUTE() do {                                                         \
    _Pragma("unroll")                                                          \
    for (int kk = 0; kk < 2; ++kk) {                                           \
      bf16x8 a0 = *(const bf16x8*)&As[wm + fr][kk * 32 + kh];                  \
      bf16x8 a1 = *(const bf16x8*)&As[wm + 16 + fr][kk * 32 + kh];             \
      bf16x8 b0 = *(const bf16x8*)&Bs[wn + fr][kk * 32 + kh];                  \
      bf16x8 b1 = *(const bf16x8*)&Bs[wn + 16 + fr][kk * 32 + kh];             \
      acc00 = __builtin_amdgcn_mfma_f32_16x16x32_bf16(a0, b0, acc00, 0, 0, 0); \
      acc01 = __builtin_amdgcn_mfma_f32_16x16x32_bf16(a0, b1, acc01, 0, 0, 0); \
      acc10 = __builtin_amdgcn_mfma_f32_16x16x32_bf16(a1, b0, acc10, 0, 0, 0); \
      acc11 = __builtin_amdgcn_mfma_f32_16x16x32_bf16(a1, b1, acc11, 0, 0, 0); \
    }                                                                          \
  } while (0)

  // prologue: tiles 0 and 1 into the two register sets
  LOADT(aX, bX0, bX1, 0);
  LOADT(aY, bY0, bY1, BK);

  for (int step = 0; step < NSTEP; step += 2) {
    STAGE(aX, bX0, bX1);
    __syncthreads();
    if (step + 2 < NSTEP) LOADT(aX, bX0, bX1, (step + 2) * BK);
    COMPUTE();
    __syncthreads();

    STAGE(aY, bY0, bY1);
    __syncthreads();
    if (step + 3 < NSTEP) LOADT(aY, bY0, bY1, (step + 3) * BK);
    COMPUTE();
    __syncthreads();
  }

  // epilogue: D layout col=lane&15, row=(lane>>4)*4+r ; store bf16 partials
  const int r4 = (lane >> 4) * 4;
  short* zp = zpart + ((size_t)ks << 20);   // slice stride 8192*128
#pragma unroll
  for (int r = 0; r < 4; ++r) {
    int gi0 = row0 + wm + r4 + r;
    int gi1 = gi0 + 16;
    zp[(size_t)gi0 * FF + wn + fr]      = f2bf(acc00[r]);
    zp[(size_t)gi0 * FF + wn + 16 + fr] = f2bf(acc01[r]);
    zp[(size_t)gi1 * FF + wn + fr]      = f2bf(acc10[r]);
    zp[(size_t)gi1 * FF + wn + 16 + fr] = f2bf(acc11[r]);
  }
#undef LOADT
#undef STAGE
#undef COMPUTE
}

// ---- kernel 4: out = relu((dinv*(sum_ks zpart + dinv*x)) @ W) ----
__global__ __launch_bounds__(256) void k_out(const short* __restrict__ zpart,
                                             const float* __restrict__ x,
                                             const float* __restrict__ dinv,
                                             const float* __restrict__ w,
                                             float* __restrict__ out) {
  __shared__ float zs[16][128];
  const int r0 = blockIdx.x * 16;
  const int tid = threadIdx.x;
#pragma unroll
  for (int half = 0; half < 2; ++half) {
    int p = half * 256 + tid;
    int r = p >> 5;
    int c4 = p & 31;
    int gi = r0 + r;
    const short* base = zpart + (size_t)gi * FF + c4 * 4;
    float s0 = 0.f, s1 = 0.f, s2 = 0.f, s3 = 0.f;
#pragma unroll
    for (int sidx = 0; sidx < KS; ++sidx) {
      short4 v = *(const short4*)(base + ((size_t)sidx << 20));
      s0 += bf2f(v.x); s1 += bf2f(v.y); s2 += bf2f(v.z); s3 += bf2f(v.w);
    }
    float4 xv = *(const float4*)(x + (size_t)gi * FF + c4 * 4);
    float di = dinv[gi];
    float di2 = di * di;
    zs[r][c4 * 4 + 0] = di * s0 + di2 * xv.x;
    zs[r][c4 * 4 + 1] = di * s1 + di2 * xv.y;
    zs[r][c4 * 4 + 2] = di * s2 + di2 * xv.z;
    zs[r][c4 * 4 + 3] = di * s3 + di2 * xv.w;
  }
  __syncthreads();
  const int f = tid & 127;
  const int rg = (tid >> 7) * 8;
  float acc[8] = {0.f, 0.f, 0.f, 0.f, 0.f, 0.f, 0.f, 0.f};
#pragma unroll 4
  for (int k = 0; k < 128; ++k) {
    float wv = w[k * FF + f];
#pragma unroll
    for (int r = 0; r < 8; ++r) acc[r] += zs[rg + r][k] * wv;
  }
#pragma unroll
  for (int r = 0; r < 8; ++r) {
    out[(size_t)(r0 + rg + r) * FF + f] = fmaxf(acc[r], 0.0f);
  }
}

extern "C" void kernel_launch(void* const* d_in, const int* in_sizes, int n_in,
                              void* d_out, int out_size, void* d_ws, size_t ws_size,
                              hipStream_t stream) {
  const float* x   = (const float*)d_in[0];
  const float* adj = (const float*)d_in[1];
  const float* w   = (const float*)d_in[2];
  float* out = (float*)d_out;

  float* dinv  = (float*)d_ws;                                  // 32 KiB @ 0
  short* yT    = (short*)((char*)d_ws + 64 * 1024);             // 2 MiB bf16 [128][8192]
  short* zpart = (short*)((char*)d_ws + 4 * 1024 * 1024);       // 16 MiB bf16 [8][8192][128]
  short* abf   = (short*)((char*)d_ws + 24 * 1024 * 1024);      // 128 MiB bf16 [8192][8192]

  k_deg_cvt<<<NN,      256, 0, stream>>>(adj, dinv, abf);
  k_scale_t<<<NN / 64, 256, 0, stream>>>(x, dinv, yT);
  k_gemm   <<<128 * KS, 512, 0, stream>>>(abf, yT, zpart);
  k_out    <<<NN / 16, 256, 0, stream>>>(zpart, x, dinv, w, out);
}

// Round 5
// 114.377 us; speedup vs baseline: 1.1964x; 1.1964x over previous
//
#include <hip/hip_runtime.h>
#include <hip/hip_bf16.h>

#define NN 8192
#define FF 128
#define BM 64
#define BK 64
#define KS 8
#define KCH (NN / KS)      // 1024 K per block
#define NSTEP (KCH / BK)   // 16

typedef __attribute__((ext_vector_type(8))) short bf16x8;   // 8 bf16 (4 VGPR)
typedef __attribute__((ext_vector_type(4))) float f32x4;

__device__ __forceinline__ short f2bf(float f) {
  unsigned u = __float_as_uint(f);
  u += 0x7FFFu + ((u >> 16) & 1u);
  return (short)(u >> 16);
}
__device__ __forceinline__ float bf2f(short s) {
  return __uint_as_float(((unsigned)(unsigned short)s) << 16);
}

// ---- kernel 1: deg[i] = rowsum(adj)+1 ; dinv[i] = (deg+1e-8)^-0.5 ----
__global__ __launch_bounds__(256) void k_deg(const float* __restrict__ adj,
                                             float* __restrict__ dinv) {
  const int row = blockIdx.x;
  const float4* p = (const float4*)(adj + (size_t)row * NN);
  float s = 0.f;
#pragma unroll
  for (int it = 0; it < 8; ++it) {
    float4 v = p[it * 256 + threadIdx.x];
    s += (v.x + v.y) + (v.z + v.w);
  }
#pragma unroll
  for (int off = 32; off > 0; off >>= 1) s += __shfl_down(s, off, 64);
  __shared__ float partial[4];
  if ((threadIdx.x & 63) == 0) partial[threadIdx.x >> 6] = s;
  __syncthreads();
  if (threadIdx.x == 0) {
    float deg = (partial[0] + partial[1]) + (partial[2] + partial[3]) + 1.0f;
    dinv[row] = 1.0f / sqrtf(deg + 1e-8f);
  }
}

// ---- kernel 2: yT[f][i] = dinv[i] * x[i][f]  (bf16, transposed for NT GEMM) ----
__global__ __launch_bounds__(256) void k_scale_t(const float* __restrict__ x,
                                                 const float* __restrict__ dinv,
                                                 short* __restrict__ yT) {
  __shared__ float tile[64][129];
  const int r0 = blockIdx.x * 64;
  const int tid = threadIdx.x;
#pragma unroll
  for (int it = 0; it < 8; ++it) {
    int q = it * 256 + tid;
    int r = q >> 5;
    int c = q & 31;
    float4 v = ((const float4*)(x + (size_t)(r0 + r) * FF))[c];
    float d = dinv[r0 + r];
    tile[r][c * 4 + 0] = v.x * d;
    tile[r][c * 4 + 1] = v.y * d;
    tile[r][c * 4 + 2] = v.z * d;
    tile[r][c * 4 + 3] = v.w * d;
  }
  __syncthreads();
  const int f = tid >> 1;
  const int i0 = (tid & 1) * 32;
#pragma unroll
  for (int g = 0; g < 4; ++g) {
    bf16x8 o;
#pragma unroll
    for (int j = 0; j < 8; ++j) o[j] = f2bf(tile[i0 + g * 8 + j][f]);
    *(bf16x8*)(yT + (size_t)f * NN + r0 + i0 + g * 8) = o;
  }
}

// ---- kernel 3: zpart[ks] = adj[:, ksliced] @ y. K-split MFMA GEMM. ----
// 1024 blocks (128 M-tiles x 8 K-slices), 512 thr = 8 waves (2M x 4N),
// BM=64, BN=128(all), BK=64. DOUBLE-buffered LDS -> ONE barrier per K-step:
// stage tile k+1 into buf^1 while MFMAs consume buf; global loads for tile
// k+2 issue before the MFMA cluster so HBM latency hides under compute.
// 2 blocks/CU (LDS 55KB, VGPR<=128) overlap each other's residual stalls.
__global__ __launch_bounds__(512, 4) void k_gemm(const float* __restrict__ adj,
                                                 const short* __restrict__ yT,
                                                 short* __restrict__ zpart) {
  __shared__ short As[2][BM][72];     // bf16, +8 pad
  __shared__ short Bs[2][128][72];
  const int tid = threadIdx.x;
  const int wave = tid >> 6;
  const int lane = tid & 63;
  const int mb = 127 - (int)(blockIdx.x & 127);   // reverse: read L3-warm rows first
  const int ks = blockIdx.x >> 7;
  const int row0 = mb * BM;
  const size_t kbase = (size_t)ks * KCH;

  // staging maps: A = 64 rows x 64 f32 (8 f32/thread); B = 128 rows x 64 bf16
  const int s_ar = tid >> 3;
  const int s_ac = (tid & 7) * 8;
  const float* pa  = adj + (size_t)(row0 + s_ar) * NN + kbase + s_ac;
  const short* pb0 = yT + (size_t)s_ar * NN + kbase + s_ac;
  const short* pb1 = yT + (size_t)(s_ar + 64) * NN + kbase + s_ac;

  const int wm = (wave >> 2) * 32;   // 0/32
  const int wn = (wave & 3) * 32;    // 0/32/64/96
  const int fr = lane & 15;
  const int kh = (lane >> 4) * 8;

  f32x4 acc00 = {0.f,0.f,0.f,0.f}, acc01 = acc00, acc10 = acc00, acc11 = acc00;

  float4 aXlo, aXhi, aYlo, aYhi;
  bf16x8 bX0, bX1, bY0, bY1;

#define LOADT(alo, ahi, b0v, b1v, koff) do {                                   \
    alo = *(const float4*)(pa + (koff));                                       \
    ahi = *(const float4*)(pa + (koff) + 4);                                   \
    b0v = *(const bf16x8*)(pb0 + (koff));                                      \
    b1v = *(const bf16x8*)(pb1 + (koff));                                      \
  } while (0)

#define STAGE(BUF, alo, ahi, b0v, b1v) do {                                    \
    bf16x8 ap_;                                                                \
    ap_[0] = f2bf(alo.x); ap_[1] = f2bf(alo.y);                                \
    ap_[2] = f2bf(alo.z); ap_[3] = f2bf(alo.w);                                \
    ap_[4] = f2bf(ahi.x); ap_[5] = f2bf(ahi.y);                                \
    ap_[6] = f2bf(ahi.z); ap_[7] = f2bf(ahi.w);                                \
    *(bf16x8*)&As[BUF][s_ar][s_ac] = ap_;                                      \
    *(bf16x8*)&Bs[BUF][s_ar][s_ac] = b0v;                                      \
    *(bf16x8*)&Bs[BUF][s_ar + 64][s_ac] = b1v;                                 \
  } while (0)

#define COMPUTE(BUF) do {                                                      \
    _Pragma("unroll")                                                          \
    for (int kk = 0; kk < 2; ++kk) {                                           \
      bf16x8 a0 = *(const bf16x8*)&As[BUF][wm + fr][kk * 32 + kh];             \
      bf16x8 a1 = *(const bf16x8*)&As[BUF][wm + 16 + fr][kk * 32 + kh];        \
      bf16x8 b0 = *(const bf16x8*)&Bs[BUF][wn + fr][kk * 32 + kh];             \
      bf16x8 b1 = *(const bf16x8*)&Bs[BUF][wn + 16 + fr][kk * 32 + kh];        \
      acc00 = __builtin_amdgcn_mfma_f32_16x16x32_bf16(a0, b0, acc00, 0, 0, 0); \
      acc01 = __builtin_amdgcn_mfma_f32_16x16x32_bf16(a0, b1, acc01, 0, 0, 0); \
      acc10 = __builtin_amdgcn_mfma_f32_16x16x32_bf16(a1, b0, acc10, 0, 0, 0); \
      acc11 = __builtin_amdgcn_mfma_f32_16x16x32_bf16(a1, b1, acc11, 0, 0, 0); \
    }                                                                          \
  } while (0)

  // prologue: tiles 0,1 into the two register sets; tile 0 staged to buf0
  LOADT(aXlo, aXhi, bX0, bX1, 0);
  LOADT(aYlo, aYhi, bY0, bY1, BK);
  STAGE(0, aXlo, aXhi, bX0, bX1);
  __syncthreads();

  for (int step = 0; step < NSTEP; step += 2) {
    // even phase: compute tile step (buf0); stage tile step+1 -> buf1;
    // issue loads for tile step+2 (land during this phase's MFMAs)
    STAGE(1, aYlo, aYhi, bY0, bY1);
    if (step + 2 < NSTEP) LOADT(aXlo, aXhi, bX0, bX1, (step + 2) * BK);
    COMPUTE(0);
    __syncthreads();
    // odd phase: compute tile step+1 (buf1); stage tile step+2 -> buf0;
    // issue loads for tile step+3
    if (step + 2 < NSTEP) STAGE(0, aXlo, aXhi, bX0, bX1);
    if (step + 3 < NSTEP) LOADT(aYlo, aYhi, bY0, bY1, (step + 3) * BK);
    COMPUTE(1);
    __syncthreads();
  }

  // epilogue: D layout col=lane&15, row=(lane>>4)*4+r ; store bf16 partials
  const int r4 = (lane >> 4) * 4;
  short* zp = zpart + ((size_t)ks << 20);   // slice stride 8192*128
#pragma unroll
  for (int r = 0; r < 4; ++r) {
    int gi0 = row0 + wm + r4 + r;
    int gi1 = gi0 + 16;
    zp[(size_t)gi0 * FF + wn + fr]      = f2bf(acc00[r]);
    zp[(size_t)gi0 * FF + wn + 16 + fr] = f2bf(acc01[r]);
    zp[(size_t)gi1 * FF + wn + fr]      = f2bf(acc10[r]);
    zp[(size_t)gi1 * FF + wn + 16 + fr] = f2bf(acc11[r]);
  }
#undef LOADT
#undef STAGE
#undef COMPUTE
}

// ---- kernel 4: out = relu((dinv*(sum_ks zpart + dinv*x)) @ W) ----
__global__ __launch_bounds__(256) void k_out(const short* __restrict__ zpart,
                                             const float* __restrict__ x,
                                             const float* __restrict__ dinv,
                                             const float* __restrict__ w,
                                             float* __restrict__ out) {
  __shared__ float zs[16][128];
  const int r0 = blockIdx.x * 16;
  const int tid = threadIdx.x;
#pragma unroll
  for (int half = 0; half < 2; ++half) {
    int p = half * 256 + tid;
    int r = p >> 5;
    int c4 = p & 31;
    int gi = r0 + r;
    const short* base = zpart + (size_t)gi * FF + c4 * 4;
    float s0 = 0.f, s1 = 0.f, s2 = 0.f, s3 = 0.f;
#pragma unroll
    for (int sidx = 0; sidx < KS; ++sidx) {
      short4 v = *(const short4*)(base + ((size_t)sidx << 20));
      s0 += bf2f(v.x); s1 += bf2f(v.y); s2 += bf2f(v.z); s3 += bf2f(v.w);
    }
    float4 xv = *(const float4*)(x + (size_t)gi * FF + c4 * 4);
    float di = dinv[gi];
    float di2 = di * di;
    zs[r][c4 * 4 + 0] = di * s0 + di2 * xv.x;
    zs[r][c4 * 4 + 1] = di * s1 + di2 * xv.y;
    zs[r][c4 * 4 + 2] = di * s2 + di2 * xv.z;
    zs[r][c4 * 4 + 3] = di * s3 + di2 * xv.w;
  }
  __syncthreads();
  const int f = tid & 127;
  const int rg = (tid >> 7) * 8;
  float acc[8] = {0.f, 0.f, 0.f, 0.f, 0.f, 0.f, 0.f, 0.f};
#pragma unroll 4
  for (int k = 0; k < 128; ++k) {
    float wv = w[k * FF + f];
#pragma unroll
    for (int r = 0; r < 8; ++r) acc[r] += zs[rg + r][k] * wv;
  }
#pragma unroll
  for (int r = 0; r < 8; ++r) {
    out[(size_t)(r0 + rg + r) * FF + f] = fmaxf(acc[r], 0.0f);
  }
}

extern "C" void kernel_launch(void* const* d_in, const int* in_sizes, int n_in,
                              void* d_out, int out_size, void* d_ws, size_t ws_size,
                              hipStream_t stream) {
  const float* x   = (const float*)d_in[0];
  const float* adj = (const float*)d_in[1];
  const float* w   = (const float*)d_in[2];
  float* out = (float*)d_out;

  float* dinv  = (float*)d_ws;                                  // 32 KiB @ 0
  short* yT    = (short*)((char*)d_ws + 64 * 1024);             // 2 MiB bf16 [128][8192]
  short* zpart = (short*)((char*)d_ws + 4 * 1024 * 1024);       // 16 MiB bf16 [8][8192][128]

  k_deg    <<<NN,      256, 0, stream>>>(adj, dinv);
  k_scale_t<<<NN / 64, 256, 0, stream>>>(x, dinv, yT);
  k_gemm   <<<128 * KS, 512, 0, stream>>>(adj, yT, zpart);
  k_out    <<<NN / 16, 256, 0, stream>>>(zpart, x, dinv, w, out);
}